// Round 5
// baseline (512.233 us; speedup 1.0000x reference)
//
#include <hip/hip_runtime.h>
#include <hip/hip_fp16.h>

#define N_NODES 100000
#define N_EDGES 1600000
#define D 128
#define SCAN_NB ((N_NODES + 1023) / 1024)   // 98
#define CHK 128                             // edge chunks
#define CHUNK_E (N_EDGES / CHK)             // 12500 edges/chunk
#define PP_STRIDE (N_NODES / 4)             // 25000 uints per chunk
#define QH 8                                // hist node groups
#define QH_N (N_NODES / QH)                 // 12500 nodes/group
#define QH_U (QH_N / 4)                     // 3125 uints (12.5 KB LDS)
#define NSH 8                               // scatter shards
#define SH_N (N_NODES / NSH)                // 12500 nodes/shard (50 KB LDS, 32-bit)

typedef _Float16 f16x4 __attribute__((ext_vector_type(4)));
typedef _Float16 f16x8 __attribute__((ext_vector_type(8)));
typedef float f32x4 __attribute__((ext_vector_type(4)));
typedef float f32x2 __attribute__((ext_vector_type(2)));

// ---------------------------------------------------------------------------
// Pass 0: fused Wt transpose (blocks [0,128)) + zero cnt_src/wsum.
__global__ __launch_bounds__(256) void
k_zwt(const float* __restrict__ W0, const float* __restrict__ W1,
      __half* __restrict__ Wt, uint4* __restrict__ zbase) {
    if (blockIdx.x < 128) {
        int i = blockIdx.x * 256 + threadIdx.x;  // over 2*D*D
        int l = i >> 14, r = i & (D * D - 1);
        int n = r >> 7, k = r & 127;
        const float* W = l ? W1 : W0;
        Wt[i] = __float2half(W[k * D + n]);
        return;
    }
    int i = (blockIdx.x - 128) * 256 + threadIdx.x;
    if (i < 2 * N_NODES / 4) zbase[i] = (uint4){0u, 0u, 0u, 0u};
}

// Pass A: dst LDS histograms, 8-bit packed; 8 node-groups x 128 chunks.
// XCD swizzle: the 8 group-blocks of a chunk land on the same XCD (read-local).
__global__ __launch_bounds__(256) void
k_hist(const int* __restrict__ dst, unsigned int* __restrict__ pp) {
    __shared__ unsigned int h[QH_U];  // 12.5 KB
    int b = blockIdx.x;               // [0, 1024)
    int xcd = b & 7, slot = b >> 3, g = slot & 7, ci = slot >> 3;
    int c = xcd * 16 + ci;
    int lo = g * QH_N;
    for (int i = threadIdx.x; i < QH_U; i += 256) h[i] = 0;
    __syncthreads();
    int e0 = c * CHUNK_E;
    for (int i = e0 + threadIdx.x; i < e0 + CHUNK_E; i += 256) {
        int v = dst[i] - lo;
        if ((unsigned)v < QH_N)
            atomicAdd(&h[v >> 2], 1u << ((v & 3) * 8));
    }
    __syncthreads();
    unsigned int* po = pp + (size_t)c * PP_STRIDE + g * QH_U;
    for (int i = threadIdx.x; i < QH_U; i += 256) po[i] = h[i];
}

// Pass B: totals -> cnt_dst; partials -> exclusive per-chunk prefix (8-bit).
__global__ void k_merge(unsigned int* __restrict__ pp, int* __restrict__ cnt_dst) {
    int u = blockIdx.x * blockDim.x + threadIdx.x;
    if (u >= PP_STRIDE) return;
    unsigned int* p = pp + u;
    int s0 = 0, s1 = 0, s2 = 0, s3 = 0;
#pragma unroll 8
    for (int c = 0; c < CHK; c++) {
        unsigned int v = p[(size_t)c * PP_STRIDE];
        p[(size_t)c * PP_STRIDE] =
            (unsigned)s0 | ((unsigned)s1 << 8) | ((unsigned)s2 << 16) | ((unsigned)s3 << 24);
        s0 += v & 255; s1 += (v >> 8) & 255; s2 += (v >> 16) & 255; s3 += (v >> 24) & 255;
    }
    cnt_dst[4 * u + 0] = s0; cnt_dst[4 * u + 1] = s1;
    cnt_dst[4 * u + 2] = s2; cnt_dst[4 * u + 3] = s3;
}

// scan cnt_dst -> rpD partial (inclusive, shifted by 1), block sums -> bsD
__global__ __launch_bounds__(1024) void
k_scan1(const int* __restrict__ cnt_dst, int* __restrict__ rpD,
        int* __restrict__ bsD) {
    __shared__ int s[1024];
    int tid = threadIdx.x;
    int i = blockIdx.x * 1024 + tid;
    int v = (i < N_NODES) ? cnt_dst[i] : 0;
    s[tid] = v;
    __syncthreads();
    for (int d = 1; d < 1024; d <<= 1) {
        int t = (tid >= d) ? s[tid - d] : 0;
        __syncthreads();
        s[tid] += t;
        __syncthreads();
    }
    if (i < N_NODES) rpD[1 + i] = s[tid];
    if (tid == 1023) bsD[blockIdx.x] = s[1023];
}

__global__ void k_scan2(int* __restrict__ bs) {
    __shared__ int s[128];
    int tid = threadIdx.x;
    int v = (tid < SCAN_NB) ? bs[tid] : 0;
    s[tid] = v;
    __syncthreads();
    for (int d = 1; d < 128; d <<= 1) {
        int t = (tid >= d) ? s[tid - d] : 0;
        __syncthreads();
        s[tid] += t;
        __syncthreads();
    }
    if (tid < SCAN_NB) bs[tid] = s[tid] - v;  // exclusive
}

// finalize rpD + nd + zero colsum (ns computed inline downstream)
__global__ void k_scan3norm(int* __restrict__ rpD, const int* __restrict__ bsD,
                            const int* __restrict__ cnt_dst,
                            float* __restrict__ nd, float* __restrict__ colsum) {
    int i = blockIdx.x * blockDim.x + threadIdx.x;
    if (i >= N_NODES) return;
    rpD[1 + i] += bsD[i >> 10];
    if (i == 0) rpD[0] = 0;
    if (i < 128) colsum[i] = 0.0f;
    nd[i] = rsqrtf((float)max(cnt_dst[i], 1));
}

// Pass C: counting-sort scatter, 8 shards x 128 chunks.
// SWIZZLE INVERTED vs round 4: XCD = shard (b&7), so each XCD's write window
// is one shard's CSR slice (~800 KB, L2-resident) -> scattered stores
// accumulate full 64B lines before writeback. Edge-list reads amplify 8x
// but are L3-resident. LDS holds 32-bit absolute cursors seeded with
// rpD + chunk-prefix: the edge loop has NO random global reads.
// Fused (1/8 interleave per block): wsum[src] += nd[dst]; cnt_src[src] += 1.
__global__ __launch_bounds__(256) void
k_scatter(const int* __restrict__ src, const int* __restrict__ dst,
          const int* __restrict__ rpD, const unsigned int* __restrict__ pp,
          const float* __restrict__ nd, int* __restrict__ csr_src,
          float* __restrict__ wsum, int* __restrict__ cnt_src) {
    __shared__ int cur[SH_N];  // 50 KB
    int b = blockIdx.x;        // [0, 1024): XCD = b & 7 (round-robin dispatch)
    int sh = b & 7, c = b >> 3;
    int lo = sh * SH_N;
    const unsigned int* pre = pp + (size_t)c * PP_STRIDE + (lo >> 2);
    for (int u = threadIdx.x; u < SH_N; u += 256) {
        int p8 = (pre[u >> 2] >> ((u & 3) * 8)) & 255;
        cur[u] = rpD[lo + u] + p8;
    }
    __syncthreads();
    int e0 = c * CHUNK_E;
    for (int i = e0 + threadIdx.x; i < e0 + CHUNK_E; i += 256) {
        int dfull = dst[i];
        int sfull = src[i];
        int d = dfull - lo;
        if ((unsigned)d < SH_N) {
            int pos = atomicAdd(&cur[d], 1);
            csr_src[pos] = sfull;
        }
        if ((i & 7) == sh) {
            unsafeAtomicAdd(&wsum[sfull], nd[dfull]);
            atomicAdd(&cnt_src[sfull], 1);
        }
    }
}

// x8[n][:] = fp8(h[n][:] * rsqrt(deg_out[n]))
__global__ void k_prep(const float* __restrict__ x, const int* __restrict__ cnt_src,
                       unsigned int* __restrict__ out) {
    int i = blockIdx.x * 256 + threadIdx.x;  // over N*D/4
    if (i >= N_NODES * (D / 4)) return;
    int n = i >> 5;
    float4 v = ((const float4*)x)[i];
    float s = rsqrtf((float)max(cnt_src[n], 1));
    int u = __builtin_amdgcn_cvt_pk_fp8_f32(v.x * s, v.y * s, 0, false);
    u = __builtin_amdgcn_cvt_pk_fp8_f32(v.z * s, v.w * s, u, true);
    out[i] = (unsigned int)u;
}

// pull SpMM (fp8 gather -> fp32 accum -> fp16 agg): one wave per node.
__global__ __launch_bounds__(256) void
k_spmm(const unsigned char* __restrict__ x8, const int* __restrict__ row_ptr,
       const int* __restrict__ csr_src, __half* __restrict__ agg) {
    int wave = (blockIdx.x * blockDim.x + threadIdx.x) >> 6;
    int lane = threadIdx.x & 63;
    int hf = lane >> 5, l32 = lane & 31;
    if (wave >= N_NODES) return;
    int beg = row_ptr[wave], end = row_ptr[wave + 1];
    float a0 = 0.f, a1 = 0.f, a2 = 0.f, a3 = 0.f;
    int j = beg;
    for (; j + 7 < end; j += 8) {
#pragma unroll
        for (int p = 0; p < 4; p++) {
            int s0 = csr_src[j + 2 * p];
            int s1 = csr_src[j + 2 * p + 1];
            int s = hf ? s1 : s0;
            unsigned int u = *(const unsigned int*)(x8 + (size_t)s * D + 4 * l32);
            f32x2 lo = __builtin_amdgcn_cvt_pk_f32_fp8(u, false);
            f32x2 hi = __builtin_amdgcn_cvt_pk_f32_fp8(u, true);
            a0 += lo[0]; a1 += lo[1]; a2 += hi[0]; a3 += hi[1];
        }
    }
    for (; j + 1 < end; j += 2) {
        int s0 = csr_src[j], s1 = csr_src[j + 1];
        int s = hf ? s1 : s0;
        unsigned int u = *(const unsigned int*)(x8 + (size_t)s * D + 4 * l32);
        f32x2 lo = __builtin_amdgcn_cvt_pk_f32_fp8(u, false);
        f32x2 hi = __builtin_amdgcn_cvt_pk_f32_fp8(u, true);
        a0 += lo[0]; a1 += lo[1]; a2 += hi[0]; a3 += hi[1];
    }
    if (j < end && hf == 0) {
        int s = csr_src[j];
        unsigned int u = *(const unsigned int*)(x8 + (size_t)s * D + 4 * l32);
        f32x2 lo = __builtin_amdgcn_cvt_pk_f32_fp8(u, false);
        f32x2 hi = __builtin_amdgcn_cvt_pk_f32_fp8(u, true);
        a0 += lo[0]; a1 += lo[1]; a2 += hi[0]; a3 += hi[1];
    }
    a0 += __shfl_xor(a0, 32, 64);
    a1 += __shfl_xor(a1, 32, 64);
    a2 += __shfl_xor(a2, 32, 64);
    a3 += __shfl_xor(a3, 32, 64);
    if (hf == 0) {
        f16x4 o;
        o[0] = (_Float16)a0; o[1] = (_Float16)a1; o[2] = (_Float16)a2; o[3] = (_Float16)a3;
        ((f16x4*)(agg + (size_t)wave * D))[l32] = o;
    }
}

// MFMA GEMM (layer 0): A fp16 (agg), out fp8 rows (pre-scaled by ns).
__global__ __launch_bounds__(256) void
k_gemm_mfma(const __half* __restrict__ A, const __half* __restrict__ Wt,
            const float* __restrict__ b, const float* __restrict__ nd,
            const int* __restrict__ cnt_src, unsigned char* __restrict__ out) {
    int w = threadIdx.x >> 6, lane = threadIdx.x & 63;
    int m = lane & 15, q = lane >> 4;
    int row0 = blockIdx.x * 128 + w * 32;

    f16x8 zf;
#pragma unroll
    for (int j = 0; j < 8; j++) zf[j] = (_Float16)0;
    f16x8 af[2][4];
#pragma unroll
    for (int g = 0; g < 2; g++) {
        int arow = row0 + g * 16 + m;
        const f16x8* pa = (const f16x8*)(A + (size_t)arow * D);
        bool aok = arow < N_NODES;
#pragma unroll
        for (int ks = 0; ks < 4; ks++) af[g][ks] = aok ? pa[ks * 4 + q] : zf;
    }

    const f16x8* pb = (const f16x8*)Wt;
    f32x4 acc[2][8];
#pragma unroll
    for (int g = 0; g < 2; g++)
#pragma unroll
        for (int nt = 0; nt < 8; nt++) acc[g][nt] = (f32x4){0.f, 0.f, 0.f, 0.f};

#pragma unroll
    for (int ks = 0; ks < 4; ks++) {
#pragma unroll
        for (int nt = 0; nt < 8; nt++) {
            f16x8 bf = pb[((nt * 16 + m) << 4) + (ks << 2) + q];
            acc[0][nt] = __builtin_amdgcn_mfma_f32_16x16x32_f16(af[0][ks], bf, acc[0][nt], 0, 0, 0);
            acc[1][nt] = __builtin_amdgcn_mfma_f32_16x16x32_f16(af[1][ks], bf, acc[1][nt], 0, 0, 0);
        }
    }

#pragma unroll
    for (int g = 0; g < 2; g++) {
        int er = row0 + g * 16 + q * 4;
        float sd[4], ss[4];
#pragma unroll
        for (int r = 0; r < 4; r++) {
            int n = er + r;
            bool ok = n < N_NODES;
            sd[r] = ok ? nd[n] : 0.0f;
            ss[r] = ok ? rsqrtf((float)max(cnt_src[n], 1)) : 0.0f;
        }
#pragma unroll
        for (int nt = 0; nt < 8; nt++) {
            int col = nt * 16 + m;
            float bc = b[col];
#pragma unroll
            for (int r = 0; r < 4; r++) {
                int n = er + r;
                if (n < N_NODES) {
                    float v = fmaxf(sd[r] * acc[g][nt][r] + bc, 0.0f) * ss[r];
                    int pk = __builtin_amdgcn_cvt_pk_fp8_f32(v, v, 0, false);
                    out[(size_t)n * D + col] = (unsigned char)(pk & 0xff);
                }
            }
        }
    }
}

// MFMA GEMM (layer 1 + fused final reduction):
// colsum[col] += sum_n ns[n]*wsum[n] * relu(nd[n]*(A@W1)[n][col] + b1[col])
__global__ __launch_bounds__(256) void
k_gemm_red(const __half* __restrict__ A, const __half* __restrict__ Wt,
           const float* __restrict__ b, const float* __restrict__ nd,
           const int* __restrict__ cnt_src, const float* __restrict__ wsum,
           float* __restrict__ colsum) {
    __shared__ float red[128];
    int tid = threadIdx.x;
    if (tid < 128) red[tid] = 0.0f;
    __syncthreads();

    int w = tid >> 6, lane = tid & 63;
    int m = lane & 15, q = lane >> 4;
    int row0 = blockIdx.x * 128 + w * 32;

    f16x8 zf;
#pragma unroll
    for (int j = 0; j < 8; j++) zf[j] = (_Float16)0;
    f16x8 af[2][4];
#pragma unroll
    for (int g = 0; g < 2; g++) {
        int arow = row0 + g * 16 + m;
        const f16x8* pa = (const f16x8*)(A + (size_t)arow * D);
        bool aok = arow < N_NODES;
#pragma unroll
        for (int ks = 0; ks < 4; ks++) af[g][ks] = aok ? pa[ks * 4 + q] : zf;
    }

    const f16x8* pb = (const f16x8*)Wt;
    f32x4 acc[2][8];
#pragma unroll
    for (int g = 0; g < 2; g++)
#pragma unroll
        for (int nt = 0; nt < 8; nt++) acc[g][nt] = (f32x4){0.f, 0.f, 0.f, 0.f};

#pragma unroll
    for (int ks = 0; ks < 4; ks++) {
#pragma unroll
        for (int nt = 0; nt < 8; nt++) {
            f16x8 bf = pb[((nt * 16 + m) << 4) + (ks << 2) + q];
            acc[0][nt] = __builtin_amdgcn_mfma_f32_16x16x32_f16(af[0][ks], bf, acc[0][nt], 0, 0, 0);
            acc[1][nt] = __builtin_amdgcn_mfma_f32_16x16x32_f16(af[1][ks], bf, acc[1][nt], 0, 0, 0);
        }
    }

    float sd[2][4], sw[2][4];
#pragma unroll
    for (int g = 0; g < 2; g++) {
        int er = row0 + g * 16 + q * 4;
#pragma unroll
        for (int r = 0; r < 4; r++) {
            int n = er + r;
            bool ok = n < N_NODES;
            sd[g][r] = ok ? nd[n] : 0.0f;
            sw[g][r] = ok ? wsum[n] * rsqrtf((float)max(cnt_src[n], 1)) : 0.0f;
        }
    }
#pragma unroll
    for (int nt = 0; nt < 8; nt++) {
        int col = nt * 16 + m;
        float bc = b[col];
        float pc = 0.0f;
#pragma unroll
        for (int g = 0; g < 2; g++)
#pragma unroll
            for (int r = 0; r < 4; r++)
                pc += sw[g][r] * fmaxf(sd[g][r] * acc[g][nt][r] + bc, 0.0f);
        atomicAdd(&red[col], pc);
    }
    __syncthreads();
    if (tid < 128) unsafeAtomicAdd(&colsum[tid], red[tid]);
}

// out[j] = (colsum/N) @ W2 [:,j] + b2[j]
__global__ void k_final(const float* __restrict__ colsum, const float* __restrict__ W,
                        const float* __restrict__ b, float* __restrict__ out) {
    __shared__ float m[128];
    int j = threadIdx.x;
    m[j] = colsum[j] * (1.0f / N_NODES);
    __syncthreads();
    float acc = b[j];
    for (int k = 0; k < 128; k++)
        acc = fmaf(m[k], W[(size_t)k * D + j], acc);
    out[j] = acc;
}

extern "C" void kernel_launch(void* const* d_in, const int* in_sizes, int n_in,
                              void* d_out, int out_size, void* d_ws, size_t ws_size,
                              hipStream_t stream) {
    const float* h   = (const float*)d_in[0];
    const int*   src = (const int*)d_in[1];
    const int*   dst = (const int*)d_in[2];
    const float* W0  = (const float*)d_in[3];
    const float* b0  = (const float*)d_in[4];
    const float* W1  = (const float*)d_in[5];
    const float* b1  = (const float*)d_in[6];
    const float* W2  = (const float*)d_in[7];
    const float* b2  = (const float*)d_in[8];
    float* out = (float*)d_out;

    // workspace (~47 MB). First 2*N words [cnt_src|wsum] are the zero region.
    int*           cnt_src = (int*)d_ws;                          // N (zeroed)
    float*         wsum    = (float*)(cnt_src + N_NODES);         // N (zeroed)
    int*           cnt_dst = (int*)(wsum + N_NODES);              // N
    float*         nd      = (float*)(cnt_dst + N_NODES);         // N
    float*         colsum  = nd + N_NODES;                        // 128
    int*           bsD     = (int*)(colsum + 128);                // 128
    int*           rpD     = bsD + 128;                           // N+1 (+3 pad)
    __half*        Wt16    = (__half*)(rpD + N_NODES + 4);        // 2*D*D halves
    int*           csr_src = (int*)(Wt16 + 2 * D * D);            // E
    unsigned int*  pp      = (unsigned int*)(csr_src + N_EDGES);  // 12.8 MB
    unsigned char* x8      = (unsigned char*)pp;                  // N*D fp8 (aliases pp)
    __half*        agg16   = (__half*)(pp + (size_t)CHK * PP_STRIDE); // N*D fp16

    // ---- CSR build (dst only) + norms + wsum ----
    k_zwt<<<128 + (2 * N_NODES / 4 + 255) / 256, 256, 0, stream>>>(
        W0, W1, Wt16, (uint4*)d_ws);
    k_hist<<<QH * CHK, 256, 0, stream>>>(dst, pp);
    k_merge<<<(PP_STRIDE + 255) / 256, 256, 0, stream>>>(pp, cnt_dst);
    k_scan1<<<SCAN_NB, 1024, 0, stream>>>(cnt_dst, rpD, bsD);
    k_scan2<<<1, 128, 0, stream>>>(bsD);
    k_scan3norm<<<(N_NODES + 255) / 256, 256, 0, stream>>>(rpD, bsD, cnt_dst,
                                                           nd, colsum);
    k_scatter<<<NSH * CHK, 256, 0, stream>>>(src, dst, rpD, pp, nd,
                                             csr_src, wsum, cnt_src);

    // x0 = fp8(h*ns)  (x8 overwrites pp region — stream-ordered after scatter)
    k_prep<<<(N_NODES * (D / 4) + 255) / 256, 256, 0, stream>>>(h, cnt_src,
                                                                (unsigned int*)x8);

    // layer 0
    k_spmm<<<(N_NODES + 3) / 4, 256, 0, stream>>>(x8, rpD, csr_src, agg16);
    k_gemm_mfma<<<(N_NODES + 127) / 128, 256, 0, stream>>>(agg16, Wt16, b0, nd,
                                                           cnt_src, x8);
    // layer 1 + fused layer-2 reduction
    k_spmm<<<(N_NODES + 3) / 4, 256, 0, stream>>>(x8, rpD, csr_src, agg16);
    k_gemm_red<<<(N_NODES + 127) / 128, 256, 0, stream>>>(agg16, Wt16 + (size_t)D * D,
                                                          b1, nd, cnt_src, wsum, colsum);
    k_final<<<1, 128, 0, stream>>>(colsum, W2, b2, out);
}

// Round 6
// 504.035 us; speedup vs baseline: 1.0163x; 1.0163x over previous
//
#include <hip/hip_runtime.h>
#include <hip/hip_fp16.h>

#define N_NODES 100000
#define N_EDGES 1600000
#define D 128
#define SCAN_NB ((N_NODES + 1023) / 1024)   // 98
#define CHK 256                             // edge chunks
#define CHUNK_E (N_EDGES / CHK)             // 6250 edges/chunk
#define PP_STRIDE (N_NODES / 4)             // 25000 uints per chunk
#define QH 2                                // hist node groups
#define QH_N (N_NODES / QH)                 // 50000 nodes/group
#define QH_U (QH_N / 4)                     // 12500 uints (50 KB LDS, 8-bit packed)
#define NSH 2                               // scatter shards
#define SH_N (N_NODES / NSH)                // 50000 nodes/shard
#define SH_U (SH_N / 4)                     // 12500 uints (50 KB LDS, 8-bit ranks)

typedef _Float16 f16x4 __attribute__((ext_vector_type(4)));
typedef _Float16 f16x8 __attribute__((ext_vector_type(8)));
typedef float f32x4 __attribute__((ext_vector_type(4)));
typedef float f32x2 __attribute__((ext_vector_type(2)));

// ---------------------------------------------------------------------------
// Pass 0: fused Wt transpose (blocks [0,128)) + zero cnt_src/wsum.
__global__ __launch_bounds__(256) void
k_zwt(const float* __restrict__ W0, const float* __restrict__ W1,
      __half* __restrict__ Wt, uint4* __restrict__ zbase) {
    if (blockIdx.x < 128) {
        int i = blockIdx.x * 256 + threadIdx.x;  // over 2*D*D
        int l = i >> 14, r = i & (D * D - 1);
        int n = r >> 7, k = r & 127;
        const float* W = l ? W1 : W0;
        Wt[i] = __float2half(W[k * D + n]);
        return;
    }
    int i = (blockIdx.x - 128) * 256 + threadIdx.x;
    if (i < 2 * N_NODES / 4) zbase[i] = (uint4){0u, 0u, 0u, 0u};
}

// Pass A: dst LDS histograms, 8-bit packed (4 nodes/uint); 2 groups x 256
// chunks = 512 blocks (>=2 blocks/CU). Fused: src out-degree atomics over
// this block's disjoint half-chunk.
__global__ __launch_bounds__(256) void
k_hist(const int* __restrict__ src, const int* __restrict__ dst,
       unsigned int* __restrict__ pp, int* __restrict__ cnt_src) {
    __shared__ unsigned int h[QH_U];  // 50 KB
    int b = blockIdx.x;               // [0, 512)
    int g = b & 1, c = b >> 1;
    int lo = g * QH_N;
    for (int i = threadIdx.x; i < QH_U; i += 256) h[i] = 0;
    __syncthreads();
    int e0 = c * CHUNK_E;
    // src out-degree: each group-block handles a disjoint half-chunk
    int s0 = e0 + g * (CHUNK_E / 2);
    for (int i = s0 + threadIdx.x; i < s0 + CHUNK_E / 2; i += 256)
        atomicAdd(&cnt_src[src[i]], 1);
    for (int i = e0 + threadIdx.x; i < e0 + CHUNK_E; i += 256) {
        int v = dst[i] - lo;
        if ((unsigned)v < QH_N)
            atomicAdd(&h[v >> 2], 1u << ((v & 3) * 8));
    }
    __syncthreads();
    unsigned int* po = pp + (size_t)c * PP_STRIDE + g * QH_U;
    for (int i = threadIdx.x; i < QH_U; i += 256) po[i] = h[i];
}

// Pass B: totals -> cnt_dst; partials -> exclusive per-chunk prefix (8-bit).
__global__ void k_merge(unsigned int* __restrict__ pp, int* __restrict__ cnt_dst) {
    int u = blockIdx.x * blockDim.x + threadIdx.x;
    if (u >= PP_STRIDE) return;
    unsigned int* p = pp + u;
    int s0 = 0, s1 = 0, s2 = 0, s3 = 0;
#pragma unroll 8
    for (int c = 0; c < CHK; c++) {
        unsigned int v = p[(size_t)c * PP_STRIDE];
        p[(size_t)c * PP_STRIDE] =
            (unsigned)s0 | ((unsigned)s1 << 8) | ((unsigned)s2 << 16) | ((unsigned)s3 << 24);
        s0 += v & 255; s1 += (v >> 8) & 255; s2 += (v >> 16) & 255; s3 += (v >> 24) & 255;
    }
    cnt_dst[4 * u + 0] = s0; cnt_dst[4 * u + 1] = s1;
    cnt_dst[4 * u + 2] = s2; cnt_dst[4 * u + 3] = s3;
}

// scan cnt_dst -> rpD partial (inclusive, shifted by 1), block sums -> bsD
__global__ __launch_bounds__(1024) void
k_scan1(const int* __restrict__ cnt_dst, int* __restrict__ rpD,
        int* __restrict__ bsD) {
    __shared__ int s[1024];
    int tid = threadIdx.x;
    int i = blockIdx.x * 1024 + tid;
    int v = (i < N_NODES) ? cnt_dst[i] : 0;
    s[tid] = v;
    __syncthreads();
    for (int d = 1; d < 1024; d <<= 1) {
        int t = (tid >= d) ? s[tid - d] : 0;
        __syncthreads();
        s[tid] += t;
        __syncthreads();
    }
    if (i < N_NODES) rpD[1 + i] = s[tid];
    if (tid == 1023) bsD[blockIdx.x] = s[1023];
}

__global__ void k_scan2(int* __restrict__ bs) {
    __shared__ int s[128];
    int tid = threadIdx.x;
    int v = (tid < SCAN_NB) ? bs[tid] : 0;
    s[tid] = v;
    __syncthreads();
    for (int d = 1; d < 128; d <<= 1) {
        int t = (tid >= d) ? s[tid - d] : 0;
        __syncthreads();
        s[tid] += t;
        __syncthreads();
    }
    if (tid < SCAN_NB) bs[tid] = s[tid] - v;  // exclusive
}

// finalize rpD + nd + zero colsum (ns computed inline downstream)
__global__ void k_scan3norm(int* __restrict__ rpD, const int* __restrict__ bsD,
                            const int* __restrict__ cnt_dst,
                            float* __restrict__ nd, float* __restrict__ colsum) {
    int i = blockIdx.x * blockDim.x + threadIdx.x;
    if (i >= N_NODES) return;
    rpD[1 + i] += bsD[i >> 10];
    if (i == 0) rpD[0] = 0;
    if (i < 128) colsum[i] = 0.0f;
    nd[i] = rsqrtf((float)max(cnt_dst[i], 1));
}

// Pass C: counting-sort scatter, 2 shards x 256 chunks = 512 blocks.
// 8-bit LDS rank counters (50 KB); per-edge p8 (chunk prefix) + rpD random
// reads are L2/L3-absorbed (proven round 0). Fused (parity interleave):
// wsum[src] += nd[dst].
__global__ __launch_bounds__(256) void
k_scatter(const int* __restrict__ src, const int* __restrict__ dst,
          const int* __restrict__ rpD, const unsigned int* __restrict__ pp,
          const float* __restrict__ nd, int* __restrict__ csr_src,
          float* __restrict__ wsum) {
    __shared__ unsigned int cur[SH_U];  // 50 KB
    int b = blockIdx.x;                 // [0, 512)
    int sh = b & 1, c = b >> 1;
    int lo = sh * SH_N;
    for (int i = threadIdx.x; i < SH_U; i += 256) cur[i] = 0;
    __syncthreads();
    int e0 = c * CHUNK_E;
    const unsigned int* pre = pp + (size_t)c * PP_STRIDE;
    for (int i = e0 + threadIdx.x; i < e0 + CHUNK_E; i += 256) {
        int dfull = dst[i];
        int sfull = src[i];
        int d = dfull - lo;
        if ((unsigned)d < SH_N) {
            int sft = (d & 3) * 8;
            int rank = (atomicAdd(&cur[d >> 2], 1u << sft) >> sft) & 255;
            int p8 = (pre[dfull >> 2] >> ((dfull & 3) * 8)) & 255;
            csr_src[rpD[dfull] + p8 + rank] = sfull;
        }
        if ((i & 1) == sh)
            unsafeAtomicAdd(&wsum[sfull], nd[dfull]);
    }
}

// x8[n][:] = fp8(h[n][:] * rsqrt(deg_out[n]))
__global__ void k_prep(const float* __restrict__ x, const int* __restrict__ cnt_src,
                       unsigned int* __restrict__ out) {
    int i = blockIdx.x * 256 + threadIdx.x;  // over N*D/4
    if (i >= N_NODES * (D / 4)) return;
    int n = i >> 5;
    float4 v = ((const float4*)x)[i];
    float s = rsqrtf((float)max(cnt_src[n], 1));
    int u = __builtin_amdgcn_cvt_pk_fp8_f32(v.x * s, v.y * s, 0, false);
    u = __builtin_amdgcn_cvt_pk_fp8_f32(v.z * s, v.w * s, u, true);
    out[i] = (unsigned int)u;
}

// pull SpMM (fp8 gather -> fp32 accum -> fp16 agg): one wave per node.
__global__ __launch_bounds__(256) void
k_spmm(const unsigned char* __restrict__ x8, const int* __restrict__ row_ptr,
       const int* __restrict__ csr_src, __half* __restrict__ agg) {
    int wave = (blockIdx.x * blockDim.x + threadIdx.x) >> 6;
    int lane = threadIdx.x & 63;
    int hf = lane >> 5, l32 = lane & 31;
    if (wave >= N_NODES) return;
    int beg = row_ptr[wave], end = row_ptr[wave + 1];
    float a0 = 0.f, a1 = 0.f, a2 = 0.f, a3 = 0.f;
    int j = beg;
    for (; j + 7 < end; j += 8) {
#pragma unroll
        for (int p = 0; p < 4; p++) {
            int s0 = csr_src[j + 2 * p];
            int s1 = csr_src[j + 2 * p + 1];
            int s = hf ? s1 : s0;
            unsigned int u = *(const unsigned int*)(x8 + (size_t)s * D + 4 * l32);
            f32x2 lo = __builtin_amdgcn_cvt_pk_f32_fp8(u, false);
            f32x2 hi = __builtin_amdgcn_cvt_pk_f32_fp8(u, true);
            a0 += lo[0]; a1 += lo[1]; a2 += hi[0]; a3 += hi[1];
        }
    }
    for (; j + 1 < end; j += 2) {
        int s0 = csr_src[j], s1 = csr_src[j + 1];
        int s = hf ? s1 : s0;
        unsigned int u = *(const unsigned int*)(x8 + (size_t)s * D + 4 * l32);
        f32x2 lo = __builtin_amdgcn_cvt_pk_f32_fp8(u, false);
        f32x2 hi = __builtin_amdgcn_cvt_pk_f32_fp8(u, true);
        a0 += lo[0]; a1 += lo[1]; a2 += hi[0]; a3 += hi[1];
    }
    if (j < end && hf == 0) {
        int s = csr_src[j];
        unsigned int u = *(const unsigned int*)(x8 + (size_t)s * D + 4 * l32);
        f32x2 lo = __builtin_amdgcn_cvt_pk_f32_fp8(u, false);
        f32x2 hi = __builtin_amdgcn_cvt_pk_f32_fp8(u, true);
        a0 += lo[0]; a1 += lo[1]; a2 += hi[0]; a3 += hi[1];
    }
    a0 += __shfl_xor(a0, 32, 64);
    a1 += __shfl_xor(a1, 32, 64);
    a2 += __shfl_xor(a2, 32, 64);
    a3 += __shfl_xor(a3, 32, 64);
    if (hf == 0) {
        f16x4 o;
        o[0] = (_Float16)a0; o[1] = (_Float16)a1; o[2] = (_Float16)a2; o[3] = (_Float16)a3;
        ((f16x4*)(agg + (size_t)wave * D))[l32] = o;
    }
}

// MFMA GEMM (layer 0): A fp16 (agg), out fp8 rows (pre-scaled by ns).
__global__ __launch_bounds__(256) void
k_gemm_mfma(const __half* __restrict__ A, const __half* __restrict__ Wt,
            const float* __restrict__ b, const float* __restrict__ nd,
            const int* __restrict__ cnt_src, unsigned char* __restrict__ out) {
    int w = threadIdx.x >> 6, lane = threadIdx.x & 63;
    int m = lane & 15, q = lane >> 4;
    int row0 = blockIdx.x * 128 + w * 32;

    f16x8 zf;
#pragma unroll
    for (int j = 0; j < 8; j++) zf[j] = (_Float16)0;
    f16x8 af[2][4];
#pragma unroll
    for (int g = 0; g < 2; g++) {
        int arow = row0 + g * 16 + m;
        const f16x8* pa = (const f16x8*)(A + (size_t)arow * D);
        bool aok = arow < N_NODES;
#pragma unroll
        for (int ks = 0; ks < 4; ks++) af[g][ks] = aok ? pa[ks * 4 + q] : zf;
    }

    const f16x8* pb = (const f16x8*)Wt;
    f32x4 acc[2][8];
#pragma unroll
    for (int g = 0; g < 2; g++)
#pragma unroll
        for (int nt = 0; nt < 8; nt++) acc[g][nt] = (f32x4){0.f, 0.f, 0.f, 0.f};

#pragma unroll
    for (int ks = 0; ks < 4; ks++) {
#pragma unroll
        for (int nt = 0; nt < 8; nt++) {
            f16x8 bf = pb[((nt * 16 + m) << 4) + (ks << 2) + q];
            acc[0][nt] = __builtin_amdgcn_mfma_f32_16x16x32_f16(af[0][ks], bf, acc[0][nt], 0, 0, 0);
            acc[1][nt] = __builtin_amdgcn_mfma_f32_16x16x32_f16(af[1][ks], bf, acc[1][nt], 0, 0, 0);
        }
    }

#pragma unroll
    for (int g = 0; g < 2; g++) {
        int er = row0 + g * 16 + q * 4;
        float sd[4], ss[4];
#pragma unroll
        for (int r = 0; r < 4; r++) {
            int n = er + r;
            bool ok = n < N_NODES;
            sd[r] = ok ? nd[n] : 0.0f;
            ss[r] = ok ? rsqrtf((float)max(cnt_src[n], 1)) : 0.0f;
        }
#pragma unroll
        for (int nt = 0; nt < 8; nt++) {
            int col = nt * 16 + m;
            float bc = b[col];
#pragma unroll
            for (int r = 0; r < 4; r++) {
                int n = er + r;
                if (n < N_NODES) {
                    float v = fmaxf(sd[r] * acc[g][nt][r] + bc, 0.0f) * ss[r];
                    int pk = __builtin_amdgcn_cvt_pk_fp8_f32(v, v, 0, false);
                    out[(size_t)n * D + col] = (unsigned char)(pk & 0xff);
                }
            }
        }
    }
}

// MFMA GEMM (layer 1 + fused final reduction):
// colsum[col] += sum_n ns[n]*wsum[n] * relu(nd[n]*(A@W1)[n][col] + b1[col])
__global__ __launch_bounds__(256) void
k_gemm_red(const __half* __restrict__ A, const __half* __restrict__ Wt,
           const float* __restrict__ b, const float* __restrict__ nd,
           const int* __restrict__ cnt_src, const float* __restrict__ wsum,
           float* __restrict__ colsum) {
    __shared__ float red[128];
    int tid = threadIdx.x;
    if (tid < 128) red[tid] = 0.0f;
    __syncthreads();

    int w = tid >> 6, lane = tid & 63;
    int m = lane & 15, q = lane >> 4;
    int row0 = blockIdx.x * 128 + w * 32;

    f16x8 zf;
#pragma unroll
    for (int j = 0; j < 8; j++) zf[j] = (_Float16)0;
    f16x8 af[2][4];
#pragma unroll
    for (int g = 0; g < 2; g++) {
        int arow = row0 + g * 16 + m;
        const f16x8* pa = (const f16x8*)(A + (size_t)arow * D);
        bool aok = arow < N_NODES;
#pragma unroll
        for (int ks = 0; ks < 4; ks++) af[g][ks] = aok ? pa[ks * 4 + q] : zf;
    }

    const f16x8* pb = (const f16x8*)Wt;
    f32x4 acc[2][8];
#pragma unroll
    for (int g = 0; g < 2; g++)
#pragma unroll
        for (int nt = 0; nt < 8; nt++) acc[g][nt] = (f32x4){0.f, 0.f, 0.f, 0.f};

#pragma unroll
    for (int ks = 0; ks < 4; ks++) {
#pragma unroll
        for (int nt = 0; nt < 8; nt++) {
            f16x8 bf = pb[((nt * 16 + m) << 4) + (ks << 2) + q];
            acc[0][nt] = __builtin_amdgcn_mfma_f32_16x16x32_f16(af[0][ks], bf, acc[0][nt], 0, 0, 0);
            acc[1][nt] = __builtin_amdgcn_mfma_f32_16x16x32_f16(af[1][ks], bf, acc[1][nt], 0, 0, 0);
        }
    }

    float sd[2][4], sw[2][4];
#pragma unroll
    for (int g = 0; g < 2; g++) {
        int er = row0 + g * 16 + q * 4;
#pragma unroll
        for (int r = 0; r < 4; r++) {
            int n = er + r;
            bool ok = n < N_NODES;
            sd[g][r] = ok ? nd[n] : 0.0f;
            sw[g][r] = ok ? wsum[n] * rsqrtf((float)max(cnt_src[n], 1)) : 0.0f;
        }
    }
#pragma unroll
    for (int nt = 0; nt < 8; nt++) {
        int col = nt * 16 + m;
        float bc = b[col];
        float pc = 0.0f;
#pragma unroll
        for (int g = 0; g < 2; g++)
#pragma unroll
            for (int r = 0; r < 4; r++)
                pc += sw[g][r] * fmaxf(sd[g][r] * acc[g][nt][r] + bc, 0.0f);
        atomicAdd(&red[col], pc);
    }
    __syncthreads();
    if (tid < 128) unsafeAtomicAdd(&colsum[tid], red[tid]);
}

// out[j] = (colsum/N) @ W2 [:,j] + b2[j]
__global__ void k_final(const float* __restrict__ colsum, const float* __restrict__ W,
                        const float* __restrict__ b, float* __restrict__ out) {
    __shared__ float m[128];
    int j = threadIdx.x;
    m[j] = colsum[j] * (1.0f / N_NODES);
    __syncthreads();
    float acc = b[j];
    for (int k = 0; k < 128; k++)
        acc = fmaf(m[k], W[(size_t)k * D + j], acc);
    out[j] = acc;
}

extern "C" void kernel_launch(void* const* d_in, const int* in_sizes, int n_in,
                              void* d_out, int out_size, void* d_ws, size_t ws_size,
                              hipStream_t stream) {
    const float* h   = (const float*)d_in[0];
    const int*   src = (const int*)d_in[1];
    const int*   dst = (const int*)d_in[2];
    const float* W0  = (const float*)d_in[3];
    const float* b0  = (const float*)d_in[4];
    const float* W1  = (const float*)d_in[5];
    const float* b1  = (const float*)d_in[6];
    const float* W2  = (const float*)d_in[7];
    const float* b2  = (const float*)d_in[8];
    float* out = (float*)d_out;

    // workspace (~60 MB). First 2*N words [cnt_src|wsum] are the zero region.
    int*           cnt_src = (int*)d_ws;                          // N (zeroed)
    float*         wsum    = (float*)(cnt_src + N_NODES);         // N (zeroed)
    int*           cnt_dst = (int*)(wsum + N_NODES);              // N
    float*         nd      = (float*)(cnt_dst + N_NODES);         // N
    float*         colsum  = nd + N_NODES;                        // 128
    int*           bsD     = (int*)(colsum + 128);                // 128
    int*           rpD     = bsD + 128;                           // N+1 (+3 pad)
    __half*        Wt16    = (__half*)(rpD + N_NODES + 4);        // 2*D*D halves
    int*           csr_src = (int*)(Wt16 + 2 * D * D);            // E
    unsigned int*  pp      = (unsigned int*)(csr_src + N_EDGES);  // 25.6 MB
    unsigned char* x8      = (unsigned char*)pp;                  // N*D fp8 (aliases pp)
    __half*        agg16   = (__half*)(pp + (size_t)CHK * PP_STRIDE); // N*D fp16

    // ---- CSR build (dst only) + norms + wsum ----
    k_zwt<<<128 + (2 * N_NODES / 4 + 255) / 256, 256, 0, stream>>>(
        W0, W1, Wt16, (uint4*)d_ws);
    k_hist<<<QH * CHK, 256, 0, stream>>>(src, dst, pp, cnt_src);
    k_merge<<<(PP_STRIDE + 255) / 256, 256, 0, stream>>>(pp, cnt_dst);
    k_scan1<<<SCAN_NB, 1024, 0, stream>>>(cnt_dst, rpD, bsD);
    k_scan2<<<1, 128, 0, stream>>>(bsD);
    k_scan3norm<<<(N_NODES + 255) / 256, 256, 0, stream>>>(rpD, bsD, cnt_dst,
                                                           nd, colsum);
    k_scatter<<<NSH * CHK, 256, 0, stream>>>(src, dst, rpD, pp, nd,
                                             csr_src, wsum);

    // x0 = fp8(h*ns)  (x8 overwrites pp region — stream-ordered after scatter)
    k_prep<<<(N_NODES * (D / 4) + 255) / 256, 256, 0, stream>>>(h, cnt_src,
                                                                (unsigned int*)x8);

    // layer 0
    k_spmm<<<(N_NODES + 3) / 4, 256, 0, stream>>>(x8, rpD, csr_src, agg16);
    k_gemm_mfma<<<(N_NODES + 127) / 128, 256, 0, stream>>>(agg16, Wt16, b0, nd,
                                                           cnt_src, x8);
    // layer 1 + fused layer-2 reduction
    k_spmm<<<(N_NODES + 3) / 4, 256, 0, stream>>>(x8, rpD, csr_src, agg16);
    k_gemm_red<<<(N_NODES + 127) / 128, 256, 0, stream>>>(agg16, Wt16 + (size_t)D * D,
                                                          b1, nd, cnt_src, wsum, colsum);
    k_final<<<1, 128, 0, stream>>>(colsum, W2, b2, out);
}

// Round 7
// 467.379 us; speedup vs baseline: 1.0960x; 1.0784x over previous
//
#include <hip/hip_runtime.h>
#include <hip/hip_fp16.h>

#define N_NODES 100000
#define N_EDGES 1600000
#define D 128
#define BKT_SHIFT 9
#define BKT_N 512                    // nodes per bucket
#define NBKT 196                     // ceil(100000/512)
#define CAP 10240                    // per-bucket packed capacity (mean 8192, sigma~90)
#define NBLK_B 512                   // bucket-kernel blocks
#define EPB (N_EDGES / NBLK_B)       // 3125 edges/block
#define ZUINT4 ((2 * N_NODES + 128) / 4)  // zero region in uint4s

typedef _Float16 f16x4 __attribute__((ext_vector_type(4)));
typedef _Float16 f16x8 __attribute__((ext_vector_type(8)));
typedef float f32x4 __attribute__((ext_vector_type(4)));
typedef float f32x2 __attribute__((ext_vector_type(2)));

// ---------------------------------------------------------------------------
// Pass 0: Wt transpose (blocks [0,128)) + zero cnt_src/wsum/colsum + gcur init.
__global__ __launch_bounds__(256) void
k_zwt(const float* __restrict__ W0, const float* __restrict__ W1,
      __half* __restrict__ Wt, uint4* __restrict__ zbase,
      unsigned int* __restrict__ gcur) {
    if (blockIdx.x < 128) {
        int i = blockIdx.x * 256 + threadIdx.x;  // over 2*D*D
        int l = i >> 14, r = i & (D * D - 1);
        int n = r >> 7, k = r & 127;
        const float* W = l ? W1 : W0;
        Wt[i] = __float2half(W[k * D + n]);
        return;
    }
    if (blockIdx.x == 128 && threadIdx.x < NBKT)
        gcur[threadIdx.x] = (unsigned)threadIdx.x * CAP;
    int i = (blockIdx.x - 128) * 256 + threadIdx.x;
    if (i < ZUINT4) zbase[i] = (uint4){0u, 0u, 0u, 0u};
}

// Phase 1: bucket the edge list by dst>>9 into per-bucket windows.
// Packed word: (dst & 511) << 17 | src  (26 bits). Per-block LDS histogram
// reserves a contiguous window per bucket -> writes fill 64B lines densely.
// Fused: cnt_src[src]++ (out-degree).
__global__ __launch_bounds__(256) void
k_bucket(const int* __restrict__ src, const int* __restrict__ dst,
         unsigned int* __restrict__ gcur, unsigned int* __restrict__ packed,
         int* __restrict__ cnt_src) {
    __shared__ int hist[NBKT];
    __shared__ unsigned int base[NBKT];
    __shared__ int cur[NBKT];
    int tid = threadIdx.x;
    for (int i = tid; i < NBKT; i += 256) hist[i] = 0;
    __syncthreads();
    int e0 = blockIdx.x * EPB;
    for (int i = e0 + tid; i < e0 + EPB; i += 256)
        atomicAdd(&hist[dst[i] >> BKT_SHIFT], 1);
    __syncthreads();
    for (int i = tid; i < NBKT; i += 256) {
        base[i] = atomicAdd(&gcur[i], (unsigned)hist[i]);
        cur[i] = 0;
    }
    __syncthreads();
    for (int i = e0 + tid; i < e0 + EPB; i += 256) {
        int d = dst[i], s = src[i];
        int b = d >> BKT_SHIFT;
        int off = atomicAdd(&cur[b], 1);
        unsigned int pos = base[b] + (unsigned)off;
        if (pos < (unsigned)(b + 1) * CAP)  // 18-sigma guard, never taken
            packed[pos] = ((unsigned)(d & (BKT_N - 1)) << 17) | (unsigned)s;
        atomicAdd(&cnt_src[s], 1);
    }
}

// Tiny scan over 196 bucket sizes -> cbase (CSR base per bucket); rpD[N]=E.
__global__ __launch_bounds__(256) void
k_cscan(const unsigned int* __restrict__ gcur, int* __restrict__ cbase,
        int* __restrict__ rpD) {
    __shared__ int sc[2][256];
    int tid = threadIdx.x;
    int m = (tid < NBKT) ? (int)(gcur[tid] - (unsigned)tid * CAP) : 0;
    sc[0][tid] = m;
    int pb = 0;
    for (int d = 1; d < 256; d <<= 1) {
        __syncthreads();
        int v = sc[pb][tid];
        if (tid >= d) v += sc[pb][tid - d];
        sc[pb ^ 1][tid] = v;
        pb ^= 1;
    }
    __syncthreads();
    cbase[tid] = tid ? sc[pb][tid - 1] : 0;
    if (tid == 255) { cbase[256] = sc[pb][255]; rpD[N_NODES] = sc[pb][255]; }
}

// Phase 2: one block per bucket. Bucket region (L2-hot) read twice:
// LDS 512-counter histogram -> LDS prefix -> rpD/nd coalesced writes ->
// in-LDS scatter of src payloads -> fully coalesced csr_src streamout.
__global__ __launch_bounds__(256) void
k_csr(const unsigned int* __restrict__ gcur, const int* __restrict__ cbase,
      const unsigned int* __restrict__ packed, int* __restrict__ csr_src,
      int* __restrict__ rpD, float* __restrict__ nd) {
    __shared__ int cnt[BKT_N];
    __shared__ int sc[2][BKT_N];
    __shared__ int outb[CAP];
    int tid = threadIdx.x;
    int b = blockIdx.x;
    int m = (int)(gcur[b] - (unsigned)b * CAP);
    if (m > CAP) m = CAP;
    int base_in = b * CAP;
    int base_out = cbase[b];
    int n0 = b * BKT_N;
    for (int j = tid; j < BKT_N; j += 256) cnt[j] = 0;
    __syncthreads();
    for (int i = tid; i < m; i += 256)
        atomicAdd(&cnt[packed[base_in + i] >> 17], 1);
    __syncthreads();
    for (int j = tid; j < BKT_N; j += 256) sc[0][j] = cnt[j];
    int pb = 0;
    for (int d = 1; d < BKT_N; d <<= 1) {
        __syncthreads();
        for (int j = tid; j < BKT_N; j += 256) {
            int v = sc[pb][j];
            if (j >= d) v += sc[pb][j - d];
            sc[pb ^ 1][j] = v;
        }
        pb ^= 1;
    }
    __syncthreads();
    for (int j = tid; j < BKT_N; j += 256) {
        int excl = j ? sc[pb][j - 1] : 0;
        int n = n0 + j;
        if (n < N_NODES) {
            rpD[n] = base_out + excl;
            nd[n] = rsqrtf((float)max(cnt[j], 1));
        }
    }
    __syncthreads();
    for (int j = tid; j < BKT_N; j += 256)
        cnt[j] = j ? sc[pb][j - 1] : 0;  // reuse as scatter cursor
    __syncthreads();
    for (int i = tid; i < m; i += 256) {
        unsigned int p = packed[base_in + i];
        int din = p >> 17;
        int off = atomicAdd(&cnt[din], 1);
        outb[off] = (int)(p & 0x1FFFFu);
    }
    __syncthreads();
    for (int i = tid; i < m; i += 256)
        csr_src[base_out + i] = outb[i];
}

// x8[n][:] = fp8(h[n][:] * rsqrt(deg_out[n]))
__global__ void k_prep(const float* __restrict__ x, const int* __restrict__ cnt_src,
                       unsigned int* __restrict__ out) {
    int i = blockIdx.x * 256 + threadIdx.x;  // over N*D/4
    if (i >= N_NODES * (D / 4)) return;
    int n = i >> 5;
    float4 v = ((const float4*)x)[i];
    float s = rsqrtf((float)max(cnt_src[n], 1));
    int u = __builtin_amdgcn_cvt_pk_fp8_f32(v.x * s, v.y * s, 0, false);
    u = __builtin_amdgcn_cvt_pk_fp8_f32(v.z * s, v.w * s, u, true);
    out[i] = (unsigned int)u;
}

// pull SpMM (fp8 gather -> fp32 accum -> fp16 agg): one wave per node.
// Optional fused wsum: wsum[src] += nd[row] (one lane per edge, fire-and-forget).
__global__ __launch_bounds__(256) void
k_spmm(const unsigned char* __restrict__ x8, const int* __restrict__ row_ptr,
       const int* __restrict__ csr_src, __half* __restrict__ agg,
       const float* __restrict__ nd, float* __restrict__ wsum) {
    int wave = (blockIdx.x * blockDim.x + threadIdx.x) >> 6;
    int lane = threadIdx.x & 63;
    int hf = lane >> 5, l32 = lane & 31;
    if (wave >= N_NODES) return;
    int beg = row_ptr[wave], end = row_ptr[wave + 1];
    float ndr = wsum ? nd[wave] : 0.0f;
    float a0 = 0.f, a1 = 0.f, a2 = 0.f, a3 = 0.f;
    int j = beg;
    for (; j + 7 < end; j += 8) {
#pragma unroll
        for (int p = 0; p < 4; p++) {
            int s0 = csr_src[j + 2 * p];
            int s1 = csr_src[j + 2 * p + 1];
            int s = hf ? s1 : s0;
            unsigned int u = *(const unsigned int*)(x8 + (size_t)s * D + 4 * l32);
            f32x2 lo = __builtin_amdgcn_cvt_pk_f32_fp8(u, false);
            f32x2 hi = __builtin_amdgcn_cvt_pk_f32_fp8(u, true);
            a0 += lo[0]; a1 += lo[1]; a2 += hi[0]; a3 += hi[1];
            if (wsum && l32 == 0) unsafeAtomicAdd(&wsum[s], ndr);
        }
    }
    for (; j + 1 < end; j += 2) {
        int s0 = csr_src[j], s1 = csr_src[j + 1];
        int s = hf ? s1 : s0;
        unsigned int u = *(const unsigned int*)(x8 + (size_t)s * D + 4 * l32);
        f32x2 lo = __builtin_amdgcn_cvt_pk_f32_fp8(u, false);
        f32x2 hi = __builtin_amdgcn_cvt_pk_f32_fp8(u, true);
        a0 += lo[0]; a1 += lo[1]; a2 += hi[0]; a3 += hi[1];
        if (wsum && l32 == 0) unsafeAtomicAdd(&wsum[s], ndr);
    }
    if (j < end && hf == 0) {
        int s = csr_src[j];
        unsigned int u = *(const unsigned int*)(x8 + (size_t)s * D + 4 * l32);
        f32x2 lo = __builtin_amdgcn_cvt_pk_f32_fp8(u, false);
        f32x2 hi = __builtin_amdgcn_cvt_pk_f32_fp8(u, true);
        a0 += lo[0]; a1 += lo[1]; a2 += hi[0]; a3 += hi[1];
        if (wsum && l32 == 0) unsafeAtomicAdd(&wsum[s], ndr);
    }
    a0 += __shfl_xor(a0, 32, 64);
    a1 += __shfl_xor(a1, 32, 64);
    a2 += __shfl_xor(a2, 32, 64);
    a3 += __shfl_xor(a3, 32, 64);
    if (hf == 0) {
        f16x4 o;
        o[0] = (_Float16)a0; o[1] = (_Float16)a1; o[2] = (_Float16)a2; o[3] = (_Float16)a3;
        ((f16x4*)(agg + (size_t)wave * D))[l32] = o;
    }
}

// MFMA GEMM (layer 0): A fp16 (agg), out fp8 rows (pre-scaled by ns).
__global__ __launch_bounds__(256) void
k_gemm_mfma(const __half* __restrict__ A, const __half* __restrict__ Wt,
            const float* __restrict__ b, const float* __restrict__ nd,
            const int* __restrict__ cnt_src, unsigned char* __restrict__ out) {
    int w = threadIdx.x >> 6, lane = threadIdx.x & 63;
    int m = lane & 15, q = lane >> 4;
    int row0 = blockIdx.x * 128 + w * 32;

    f16x8 zf;
#pragma unroll
    for (int j = 0; j < 8; j++) zf[j] = (_Float16)0;
    f16x8 af[2][4];
#pragma unroll
    for (int g = 0; g < 2; g++) {
        int arow = row0 + g * 16 + m;
        const f16x8* pa = (const f16x8*)(A + (size_t)arow * D);
        bool aok = arow < N_NODES;
#pragma unroll
        for (int ks = 0; ks < 4; ks++) af[g][ks] = aok ? pa[ks * 4 + q] : zf;
    }

    const f16x8* pb = (const f16x8*)Wt;
    f32x4 acc[2][8];
#pragma unroll
    for (int g = 0; g < 2; g++)
#pragma unroll
        for (int nt = 0; nt < 8; nt++) acc[g][nt] = (f32x4){0.f, 0.f, 0.f, 0.f};

#pragma unroll
    for (int ks = 0; ks < 4; ks++) {
#pragma unroll
        for (int nt = 0; nt < 8; nt++) {
            f16x8 bf = pb[((nt * 16 + m) << 4) + (ks << 2) + q];
            acc[0][nt] = __builtin_amdgcn_mfma_f32_16x16x32_f16(af[0][ks], bf, acc[0][nt], 0, 0, 0);
            acc[1][nt] = __builtin_amdgcn_mfma_f32_16x16x32_f16(af[1][ks], bf, acc[1][nt], 0, 0, 0);
        }
    }

#pragma unroll
    for (int g = 0; g < 2; g++) {
        int er = row0 + g * 16 + q * 4;
        float sd[4], ss[4];
#pragma unroll
        for (int r = 0; r < 4; r++) {
            int n = er + r;
            bool ok = n < N_NODES;
            sd[r] = ok ? nd[n] : 0.0f;
            ss[r] = ok ? rsqrtf((float)max(cnt_src[n], 1)) : 0.0f;
        }
#pragma unroll
        for (int nt = 0; nt < 8; nt++) {
            int col = nt * 16 + m;
            float bc = b[col];
#pragma unroll
            for (int r = 0; r < 4; r++) {
                int n = er + r;
                if (n < N_NODES) {
                    float v = fmaxf(sd[r] * acc[g][nt][r] + bc, 0.0f) * ss[r];
                    int pk = __builtin_amdgcn_cvt_pk_fp8_f32(v, v, 0, false);
                    out[(size_t)n * D + col] = (unsigned char)(pk & 0xff);
                }
            }
        }
    }
}

// MFMA GEMM (layer 1 + fused final reduction):
// colsum[col] += sum_n ns[n]*wsum[n] * relu(nd[n]*(A@W1)[n][col] + b1[col])
__global__ __launch_bounds__(256) void
k_gemm_red(const __half* __restrict__ A, const __half* __restrict__ Wt,
           const float* __restrict__ b, const float* __restrict__ nd,
           const int* __restrict__ cnt_src, const float* __restrict__ wsum,
           float* __restrict__ colsum) {
    __shared__ float red[128];
    int tid = threadIdx.x;
    if (tid < 128) red[tid] = 0.0f;
    __syncthreads();

    int w = tid >> 6, lane = tid & 63;
    int m = lane & 15, q = lane >> 4;
    int row0 = blockIdx.x * 128 + w * 32;

    f16x8 zf;
#pragma unroll
    for (int j = 0; j < 8; j++) zf[j] = (_Float16)0;
    f16x8 af[2][4];
#pragma unroll
    for (int g = 0; g < 2; g++) {
        int arow = row0 + g * 16 + m;
        const f16x8* pa = (const f16x8*)(A + (size_t)arow * D);
        bool aok = arow < N_NODES;
#pragma unroll
        for (int ks = 0; ks < 4; ks++) af[g][ks] = aok ? pa[ks * 4 + q] : zf;
    }

    const f16x8* pb = (const f16x8*)Wt;
    f32x4 acc[2][8];
#pragma unroll
    for (int g = 0; g < 2; g++)
#pragma unroll
        for (int nt = 0; nt < 8; nt++) acc[g][nt] = (f32x4){0.f, 0.f, 0.f, 0.f};

#pragma unroll
    for (int ks = 0; ks < 4; ks++) {
#pragma unroll
        for (int nt = 0; nt < 8; nt++) {
            f16x8 bf = pb[((nt * 16 + m) << 4) + (ks << 2) + q];
            acc[0][nt] = __builtin_amdgcn_mfma_f32_16x16x32_f16(af[0][ks], bf, acc[0][nt], 0, 0, 0);
            acc[1][nt] = __builtin_amdgcn_mfma_f32_16x16x32_f16(af[1][ks], bf, acc[1][nt], 0, 0, 0);
        }
    }

    float sd[2][4], sw[2][4];
#pragma unroll
    for (int g = 0; g < 2; g++) {
        int er = row0 + g * 16 + q * 4;
#pragma unroll
        for (int r = 0; r < 4; r++) {
            int n = er + r;
            bool ok = n < N_NODES;
            sd[g][r] = ok ? nd[n] : 0.0f;
            sw[g][r] = ok ? wsum[n] * rsqrtf((float)max(cnt_src[n], 1)) : 0.0f;
        }
    }
#pragma unroll
    for (int nt = 0; nt < 8; nt++) {
        int col = nt * 16 + m;
        float bc = b[col];
        float pc = 0.0f;
#pragma unroll
        for (int g = 0; g < 2; g++)
#pragma unroll
            for (int r = 0; r < 4; r++)
                pc += sw[g][r] * fmaxf(sd[g][r] * acc[g][nt][r] + bc, 0.0f);
        atomicAdd(&red[col], pc);
    }
    __syncthreads();
    if (tid < 128) unsafeAtomicAdd(&colsum[tid], red[tid]);
}

// out[j] = (colsum/N) @ W2 [:,j] + b2[j]
__global__ void k_final(const float* __restrict__ colsum, const float* __restrict__ W,
                        const float* __restrict__ b, float* __restrict__ out) {
    __shared__ float m[128];
    int j = threadIdx.x;
    m[j] = colsum[j] * (1.0f / N_NODES);
    __syncthreads();
    float acc = b[j];
    for (int k = 0; k < 128; k++)
        acc = fmaf(m[k], W[(size_t)k * D + j], acc);
    out[j] = acc;
}

extern "C" void kernel_launch(void* const* d_in, const int* in_sizes, int n_in,
                              void* d_out, int out_size, void* d_ws, size_t ws_size,
                              hipStream_t stream) {
    const float* h   = (const float*)d_in[0];
    const int*   src = (const int*)d_in[1];
    const int*   dst = (const int*)d_in[2];
    const float* W0  = (const float*)d_in[3];
    const float* b0  = (const float*)d_in[4];
    const float* W1  = (const float*)d_in[5];
    const float* b1  = (const float*)d_in[6];
    const float* W2  = (const float*)d_in[7];
    const float* b2  = (const float*)d_in[8];
    float* out = (float*)d_out;

    // workspace (~47 MB). [cnt_src|wsum|colsum] = zero region.
    int*           cnt_src = (int*)d_ws;                          // N (zeroed)
    float*         wsum    = (float*)(cnt_src + N_NODES);         // N (zeroed)
    float*         colsum  = wsum + N_NODES;                      // 128 (zeroed)
    float*         nd      = colsum + 128;                        // N
    int*           rpD     = (int*)(nd + N_NODES);                // N+1 (+3 pad)
    unsigned int*  gcur    = (unsigned int*)(rpD + N_NODES + 4);  // 256
    int*           cbase   = (int*)(gcur + 256);                  // 257 (+3 pad)
    __half*        Wt16    = (__half*)(cbase + 260);              // 2*D*D halves
    int*           csr_src = (int*)(Wt16 + 2 * D * D);            // E
    unsigned int*  packed  = (unsigned int*)(csr_src + N_EDGES);  // NBKT*CAP (8 MB)
    unsigned char* x8      = (unsigned char*)packed;              // N*D fp8 (12.8 MB, aliases packed)
    __half*        agg16   = (__half*)(x8 + (size_t)N_NODES * D); // N*D fp16

    // ---- CSR build via two-phase bucket sort ----
    k_zwt<<<128 + (ZUINT4 + 255) / 256, 256, 0, stream>>>(
        W0, W1, Wt16, (uint4*)d_ws, gcur);
    k_bucket<<<NBLK_B, 256, 0, stream>>>(src, dst, gcur, packed, cnt_src);
    k_cscan<<<1, 256, 0, stream>>>(gcur, cbase, rpD);
    k_csr<<<NBKT, 256, 0, stream>>>(gcur, cbase, packed, csr_src, rpD, nd);

    // x0 = fp8(h*ns)  (x8 overwrites packed — stream-ordered after k_csr)
    k_prep<<<(N_NODES * (D / 4) + 255) / 256, 256, 0, stream>>>(h, cnt_src,
                                                                (unsigned int*)x8);

    // layer 0
    k_spmm<<<(N_NODES + 3) / 4, 256, 0, stream>>>(x8, rpD, csr_src, agg16,
                                                  nd, (float*)nullptr);
    k_gemm_mfma<<<(N_NODES + 127) / 128, 256, 0, stream>>>(agg16, Wt16, b0, nd,
                                                           cnt_src, x8);
    // layer 1 (+ fused wsum) + fused layer-2 reduction
    k_spmm<<<(N_NODES + 3) / 4, 256, 0, stream>>>(x8, rpD, csr_src, agg16,
                                                  nd, wsum);
    k_gemm_red<<<(N_NODES + 127) / 128, 256, 0, stream>>>(agg16, Wt16 + (size_t)D * D,
                                                          b1, nd, cnt_src, wsum, colsum);
    k_final<<<1, 128, 0, stream>>>(colsum, W2, b2, out);
}